// Round 2
// 385.204 us; speedup vs baseline: 1.0649x; 1.0649x over previous
//
#include <hip/hip_runtime.h>

// bf16 stored as raw ushort everywhere; MFMA consumes __bf16 vectors.
typedef unsigned short u16;
using bf16x8  = __attribute__((ext_vector_type(8))) __bf16;
using floatx4 = __attribute__((ext_vector_type(4))) float;

__device__ __forceinline__ u16 f2bf(float f) {
  unsigned int u = __builtin_bit_cast(unsigned int, f);
  u += 0x7fffu + ((u >> 16) & 1u);          // round-to-nearest-even
  return (u16)(u >> 16);
}
__device__ __forceinline__ float bf2f(u16 h) {
  unsigned int u = ((unsigned int)h) << 16;
  return __builtin_bit_cast(float, u);
}

#define AS1(p) ((const __attribute__((address_space(1))) void*)(p))
#define AS3(p) ((__attribute__((address_space(3))) void*)(p))

// ================= OLD 128x128 engine (kept for qkv / bt) =================
#define GEMM_PROLOGUE_AT(bmv, bnv)                                           \
  __shared__ u16 As[128 * 32];                                               \
  __shared__ u16 Bs[128 * 32];                                               \
  const int tid  = threadIdx.x;                                              \
  const int wave = tid >> 6, lane = tid & 63;                                \
  const int wm = (wave >> 1) * 64, wn = (wave & 1) * 64;                     \
  const long bm = (bmv), bn = (bnv);                                         \
  floatx4 acc[4][4] = {};                                                    \
  const int srow = lane >> 2;                                                \
  const int scol = (lane & 3) * 8;                                           \
  const int c0 = wave * 2, c1 = c0 + 1;                                      \
  const int fr = lane & 15;                                                  \
  const int kq = (lane >> 4) * 8;                                            \
  const int oc = (lane >> 4) * 4;   /* swapped layout: col quad offset */

#define GEMM_PROLOGUE() GEMM_PROLOGUE_AT((long)blockIdx.y * 128, (long)blockIdx.x * 128)

#define GEMM_STAGE(Ab, Bb, K, k0)                                            \
    __syncthreads();                                                         \
    __builtin_amdgcn_global_load_lds(AS1(Ab + (long)(c0*16 + srow)*K + k0 + scol), AS3(As + c0*512), 16, 0, 0); \
    __builtin_amdgcn_global_load_lds(AS1(Ab + (long)(c1*16 + srow)*K + k0 + scol), AS3(As + c1*512), 16, 0, 0); \
    __builtin_amdgcn_global_load_lds(AS1(Bb + (long)(c0*16 + srow)*K + k0 + scol), AS3(Bs + c0*512), 16, 0, 0); \
    __builtin_amdgcn_global_load_lds(AS1(Bb + (long)(c1*16 + srow)*K + k0 + scol), AS3(Bs + c1*512), 16, 0, 0); \
    __syncthreads();                                                         \
    bf16x8 af[4], bfv[4];                                                    \
    _Pragma("unroll")                                                        \
    for (int mi = 0; mi < 4; ++mi)                                           \
      af[mi] = *(const bf16x8*)(As + (wm + mi*16 + fr)*32 + kq);             \
    _Pragma("unroll")                                                        \
    for (int ni = 0; ni < 4; ++ni)                                           \
      bfv[ni] = *(const bf16x8*)(Bs + (wn + ni*16 + fr)*32 + kq);

#define GEMM_KSTEP(Ab, Bb, K, k0)                                            \
  {                                                                          \
    GEMM_STAGE(Ab, Bb, K, k0)                                                \
    _Pragma("unroll")                                                        \
    for (int mi = 0; mi < 4; ++mi)                                           \
      _Pragma("unroll")                                                      \
      for (int ni = 0; ni < 4; ++ni)                                         \
        acc[mi][ni] = __builtin_amdgcn_mfma_f32_16x16x32_bf16(af[mi], bfv[ni], acc[mi][ni], 0, 0, 0); \
  }

#define GEMM_KSTEP_SWAP(Ab, Bb, K, k0)                                       \
  {                                                                          \
    GEMM_STAGE(Ab, Bb, K, k0)                                                \
    _Pragma("unroll")                                                        \
    for (int mi = 0; mi < 4; ++mi)                                           \
      _Pragma("unroll")                                                      \
      for (int ni = 0; ni < 4; ++ni)                                         \
        acc[mi][ni] = __builtin_amdgcn_mfma_f32_16x16x32_bf16(bfv[ni], af[mi], acc[mi][ni], 0, 0, 0); \
  }

// ============ NEW 256x256 8-wave phased engine (BK=32, 4-slot ring) ========
// LDS ring: 4 slots x (A 16KB + B 16KB) = 128 KiB. Subtiled [16][16rows][32k]
// bf16 per operand-slot, st_16x32 XOR swizzle (byte ^= ((byte>>9)&1)<<5).
// Schedule per K-tile (2 phases of 16 MFMA): counted vmcnt(6) once per tile
// (tail 4 -> 0), stage units 5..6 ahead, slot overwritten >=2 phases after
// its last reader. T2 swizzle + T4 counted waits + T5 setprio.
#define NE_PROLOGUE(bmv, bnv)                                                \
  __shared__ u16 lds[65536];            /* 128 KiB */                        \
  const int tid = threadIdx.x;                                               \
  const int w = tid >> 6, lane = tid & 63;                                   \
  const int wm = (w >> 2) * 128, wn = (w & 3) * 64;                          \
  const int wm16 = (w >> 2) * 8;        /* A subtile base for this wave */   \
  const int wn4  = (w & 3) * 4;         /* B subtile base for this wave */   \
  const long bm = (bmv), bn = (bnv);                                         \
  floatx4 acc[8][4] = {};                                                    \
  const int fr = lane & 15;                                                  \
  const int kq = (lane >> 4) * 8;                                            \
  const int oc = (lane >> 4) * 4;                                            \
  /* staging: linear LDS dest (lane*16); source is inverse-swizzled */       \
  const int swz  = (lane * 16) ^ (((lane >> 5) & 1) << 5);                   \
  const int srow = swz >> 6;            /* [0,16) row within subtile */      \
  const int scol = (swz & 63) >> 1;     /* {0,8,16,24} k within tile */      \
  const int st0  = w * 2;               /* this wave's subtile pair */       \
  /* read-side swizzled byte offset within a subtile */                      \
  const int aoff = fr * 64 + ((kq * 2) ^ (((fr >> 3) & 1) << 5));

#define NE_SETUP_PTRS(Abp, Bbp, ldK)                                         \
  const u16* A0p = (Abp) + (long)(st0 * 16 + srow) * (ldK) + scol;           \
  const u16* A1p = A0p + 16L * (ldK);                                        \
  const u16* B0p = (Bbp) + (long)(st0 * 16 + srow) * (ldK) + scol;           \
  const u16* B1p = B0p + 16L * (ldK);

#define NE_SA(T)                                                             \
  { u16* d_ = lds + (((T) & 3) * 16384) + st0 * 512;                         \
    long o_ = (long)(T) * 32;                                                \
    __builtin_amdgcn_global_load_lds(AS1(A0p + o_), AS3(d_), 16, 0, 0);      \
    __builtin_amdgcn_global_load_lds(AS1(A1p + o_), AS3(d_ + 512), 16, 0, 0); }
#define NE_SB(T)                                                             \
  { u16* d_ = lds + (((T) & 3) * 16384) + 8192 + st0 * 512;                  \
    long o_ = (long)(T) * 32;                                                \
    __builtin_amdgcn_global_load_lds(AS1(B0p + o_), AS3(d_), 16, 0, 0);      \
    __builtin_amdgcn_global_load_lds(AS1(B1p + o_), AS3(d_ + 512), 16, 0, 0); }

// One K-tile = 2 phases. Phase0: read A(lo)+B, stage B(T+2), 16 MFMA.
// Phase1: read A(hi), stage A(T+3), 16 MFMA, counted vmcnt, barrier.
#define NE_TILE(T, NT)                                                       \
  {                                                                          \
    const char* sb_ = (const char*)lds + ((T) & 3) * 32768;                  \
    bf16x8 af[4], bf[4];                                                     \
    _Pragma("unroll")                                                        \
    for (int i = 0; i < 4; ++i)                                              \
      af[i] = *(const bf16x8*)(sb_ + (wm16 + i) * 1024 + aoff);              \
    _Pragma("unroll")                                                        \
    for (int i = 0; i < 4; ++i)                                              \
      bf[i] = *(const bf16x8*)(sb_ + 16384 + (wn4 + i) * 1024 + aoff);       \
    if ((T) + 2 < (NT)) NE_SB((T) + 2)                                       \
    __builtin_amdgcn_s_barrier();                                            \
    asm volatile("s_waitcnt lgkmcnt(0)" ::: "memory");                       \
    __builtin_amdgcn_sched_barrier(0);                                       \
    __builtin_amdgcn_s_setprio(1);                                           \
    _Pragma("unroll")                                                        \
    for (int mi = 0; mi < 4; ++mi)                                           \
      _Pragma("unroll")                                                      \
      for (int ni = 0; ni < 4; ++ni)                                         \
        acc[mi][ni] = __builtin_amdgcn_mfma_f32_16x16x32_bf16(bf[ni], af[mi], acc[mi][ni], 0, 0, 0); \
    __builtin_amdgcn_s_setprio(0);                                           \
    __builtin_amdgcn_s_barrier();                                            \
    __builtin_amdgcn_sched_barrier(0);                                       \
    _Pragma("unroll")                                                        \
    for (int i = 0; i < 4; ++i)                                              \
      af[i] = *(const bf16x8*)(sb_ + (wm16 + 4 + i) * 1024 + aoff);          \
    if ((T) + 3 < (NT)) NE_SA((T) + 3)                                       \
    __builtin_amdgcn_s_barrier();                                            \
    asm volatile("s_waitcnt lgkmcnt(0)" ::: "memory");                       \
    __builtin_amdgcn_sched_barrier(0);                                       \
    __builtin_amdgcn_s_setprio(1);                                           \
    _Pragma("unroll")                                                        \
    for (int mi = 0; mi < 4; ++mi)                                           \
      _Pragma("unroll")                                                      \
      for (int ni = 0; ni < 4; ++ni)                                         \
        acc[4 + mi][ni] = __builtin_amdgcn_mfma_f32_16x16x32_bf16(bf[ni], af[mi], acc[4 + mi][ni], 0, 0, 0); \
    __builtin_amdgcn_s_setprio(0);                                           \
    if ((T) < (NT) - 3)       { asm volatile("s_waitcnt vmcnt(6)" ::: "memory"); } \
    else if ((T) == (NT) - 3) { asm volatile("s_waitcnt vmcnt(4)" ::: "memory"); } \
    else if ((T) == (NT) - 2) { asm volatile("s_waitcnt vmcnt(0)" ::: "memory"); } \
    __builtin_amdgcn_s_barrier();                                            \
    __builtin_amdgcn_sched_barrier(0);                                       \
  }

#define NE_START()                                                           \
  NE_SA(0) NE_SB(0) NE_SA(1) NE_SB(1) NE_SA(2)                               \
  asm volatile("s_waitcnt vmcnt(6)" ::: "memory");                           \
  __builtin_amdgcn_s_barrier();                                              \
  __builtin_amdgcn_sched_barrier(0);

// Final projection: C = A*Bt^T + bias, fp32 out, swapped epilogue (float4).
__global__ __launch_bounds__(256) void gemm_bt(
    const u16* __restrict__ A, const u16* __restrict__ Bt,
    float* __restrict__ Cout, const float* __restrict__ bias, int N, int K)
{
  GEMM_PROLOGUE();
  const u16* Ab = A + bm * K;
  const u16* Bb = Bt + bn * K;
  for (int k0 = 0; k0 < K; k0 += 32) GEMM_KSTEP_SWAP(Ab, Bb, K, k0);

#pragma unroll
  for (int mi = 0; mi < 4; ++mi) {
    long row = bm + wm + mi*16 + fr;
#pragma unroll
    for (int ni = 0; ni < 4; ++ni) {
      long colb = bn + wn + ni*16 + oc;
      float4 bv4 = *(const float4*)(bias + colb);
      float4 o;
      o.x = acc[mi][ni][0] + bv4.x;
      o.y = acc[mi][ni][1] + bv4.y;
      o.z = acc[mi][ni][2] + bv4.z;
      o.w = acc[mi][ni][3] + bv4.w;
      *(float4*)(Cout + row * N + colb) = o;
    }
  }
}

// Batch-combined QK^T + unnormalized exp — NEW phased 256^2 engine.
// Grid (8,64) = 512 blocks x 512 thr. xcd = blockIdx.x; b = xcd>>2; each XCD
// owns a 4-row by-band of one batch. P[b] = exp(scale*q k^T) bf16;
// lpartT[b][row][64] fp32 (64-col group partial rowsums, layout unchanged).
__global__ __launch_bounds__(512, 2) void gemm_qk_exp(
    const u16* __restrict__ q, const u16* __restrict__ k,
    u16* __restrict__ probs, float* __restrict__ lpartT, float alpha)
{
  const int N = 4096;
  const int xcd = blockIdx.x;
  const int j = blockIdx.y;
  const long b = xcd >> 2;
  const int by = (xcd & 3) * 4 + (j & 3);   // [0,16)
  const int bx = j >> 2;                    // [0,16)

  NE_PROLOGUE((long)by * 256, (long)bx * 256);
  const u16* Ab = q + b * 4096 * 1024 + bm * 1024;
  const u16* Bb = k + b * 4096 * 1024 + bn * 1024;
  NE_SETUP_PTRS(Ab, Bb, 1024);
  u16* P = probs + b * 4096L * 4096;
  float* lp = lpartT + b * 4096 * 64;

  NE_START()
  for (int T = 0; T < 32; ++T) NE_TILE(T, 32)

  const float a2 = alpha * 1.44269504f;     // exp(x*alpha) = exp2(x*a2)
  const int cg = bx * 4 + (w & 3);          // 64-col group index
#pragma unroll
  for (int mi = 0; mi < 8; ++mi) {
    long row = bm + wm + mi * 16 + fr;
    float rs = 0.f;
#pragma unroll
    for (int ni = 0; ni < 4; ++ni) {
      long colb = bn + wn + ni * 16 + oc;
      float e0 = __builtin_amdgcn_exp2f(acc[mi][ni][0] * a2);
      float e1 = __builtin_amdgcn_exp2f(acc[mi][ni][1] * a2);
      float e2 = __builtin_amdgcn_exp2f(acc[mi][ni][2] * a2);
      float e3 = __builtin_amdgcn_exp2f(acc[mi][ni][3] * a2);
      rs += (e0 + e1) + (e2 + e3);
      ushort4 o;
      o.x = f2bf(e0); o.y = f2bf(e1); o.z = f2bf(e2); o.w = f2bf(e3);
      *(ushort4*)(P + row * N + colb) = o;
    }
    rs += __shfl_xor(rs, 16);
    rs += __shfl_xor(rs, 32);
    if (lane < 16)
      lp[(bm + wm + mi * 16 + lane) * 64 + cg] = rs;
  }
}

// Batch-combined PV, split-K=2 — NEW phased 256^2 engine.
// Grid (8,32) = 256 blocks x 512 thr = exactly 1 block/CU, one full round.
// xcd = b*4 + sp*2 + half: each XCD streams one 8MB probs slice + 4MB vT
// slice (L2-resident). Partials bf16 [2 sp][4096][1024] per batch.
__global__ __launch_bounds__(512, 2) void gemm_pv_splitk2(
    const u16* __restrict__ probs, const u16* __restrict__ vT,
    u16* __restrict__ pA, u16* __restrict__ pB)
{
  const int xcd = blockIdx.x;
  const int j = blockIdx.y;
  const long b = xcd >> 2;
  const int sp = (xcd >> 1) & 1;
  const int by = (xcd & 1) * 8 + (j & 7);   // [0,16)
  const int bx = j >> 3;                    // [0,4)

  NE_PROLOGUE((long)by * 256, (long)bx * 256);
  const u16* Ab = probs + b * 4096L * 4096 + bm * 4096 + sp * 2048;
  const u16* Bb = vT + b * 1024L * 4096 + bn * 4096 + sp * 2048;
  NE_SETUP_PTRS(Ab, Bb, 4096);
  u16* part = (b ? pB : pA) + (long)sp * 4096 * 1024;

  NE_START()
  for (int T = 0; T < 64; ++T) NE_TILE(T, 64)

#pragma unroll
  for (int mi = 0; mi < 8; ++mi) {
    long row = bm + wm + mi * 16 + fr;
#pragma unroll
    for (int ni = 0; ni < 4; ++ni) {
      long colb = bn + wn + ni * 16 + oc;
      ushort4 o;
      o.x = f2bf(acc[mi][ni][0]);
      o.y = f2bf(acc[mi][ni][1]);
      o.z = f2bf(acc[mi][ni][2]);
      o.w = f2bf(acc[mi][ni][3]);
      *(ushort4*)(part + row * 1024 + colb) = o;
    }
  }
}

// Fused QKV projection: A=xb [8192,1024], Bt=WqkvT [3072,1024], grid (24,64).
__global__ __launch_bounds__(256) void gemm_qkv(
    const u16* __restrict__ A, const u16* __restrict__ Bt,
    u16* __restrict__ qb, u16* __restrict__ kb, u16* __restrict__ vT,
    const float* __restrict__ bq, const float* __restrict__ bk,
    const float* __restrict__ bv)
{
  const int K = 1024;
  GEMM_PROLOGUE();
  const u16* Ab = A + bm * K;
  const u16* Bb = Bt + bn * K;

  if (bn < 2048) {
    for (int k0 = 0; k0 < K; k0 += 32) GEMM_KSTEP_SWAP(Ab, Bb, K, k0);
    u16* C = (bn < 1024) ? qb : kb;
    const float* bias = (bn < 1024) ? bq : bk;
#pragma unroll
    for (int mi = 0; mi < 4; ++mi) {
      long row = bm + wm + mi*16 + fr;
#pragma unroll
      for (int ni = 0; ni < 4; ++ni) {
        long colg = bn + wn + ni*16 + oc;
        long cc = colg & 1023;
        float4 bv4 = *(const float4*)(bias + cc);
        ushort4 o;
        o.x = f2bf(acc[mi][ni][0] + bv4.x);
        o.y = f2bf(acc[mi][ni][1] + bv4.y);
        o.z = f2bf(acc[mi][ni][2] + bv4.z);
        o.w = f2bf(acc[mi][ni][3] + bv4.w);
        *(ushort4*)(C + row * 1024 + cc) = o;
      }
    }
  } else {
    for (int k0 = 0; k0 < K; k0 += 32) GEMM_KSTEP(Ab, Bb, K, k0);
    const int orow = (lane >> 4) * 4;
    const int ocol = lane & 15;
#pragma unroll
    for (int ni = 0; ni < 4; ++ni) {
      long col = bn + wn + ni*16 + ocol;
      float bvv = bv[col - 2048];
#pragma unroll
      for (int mi = 0; mi < 4; ++mi) {
        long row = bm + wm + mi*16 + orow;
        long b_ = row >> 12, s = row & 4095, d = col - 2048;
        ushort4 o;
        o.x = f2bf(acc[mi][ni][0] + bvv);
        o.y = f2bf(acc[mi][ni][1] + bvv);
        o.z = f2bf(acc[mi][ni][2] + bvv);
        o.w = f2bf(acc[mi][ni][3] + bvv);
        *(ushort4*)(vT + b_ * (1024L * 4096) + d * 4096L + s) = o;
      }
    }
  }
}

// Combined reduce + softmax-normalize: grid (4096 rows, 2 batches).
// Wave 0 reads the row's 64 lpartT entries, shuffle-sums, broadcasts;
// out[b][row] = (s0+s1)/l as bf16 (2 split-K partials now).
__global__ __launch_bounds__(256) void reduce2_div_row(
    const u16* __restrict__ pA, const u16* __restrict__ pB,
    const float* __restrict__ lpartT, u16* __restrict__ ob)
{
  const int row = blockIdx.x;           // [0,4096)
  const long b = blockIdx.y;
  const int tid = threadIdx.x;
  const u16* part = b ? pB : pA;
  const float* lp = lpartT + b * 4096 * 64;
  __shared__ float sl;
  if (tid < 64) {
    float s = lp[(long)row * 64 + tid];
#pragma unroll
    for (int off = 32; off; off >>= 1) s += __shfl_down(s, off);
    if (tid == 0) sl = s;
  }
  __syncthreads();
  const float inv = 1.0f / sl;
  const long base = (long)row * 1024 + tid * 4;
  float acc4[4] = {0.f, 0.f, 0.f, 0.f};
#pragma unroll
  for (int s = 0; s < 2; ++s) {
    ushort4 p = *(const ushort4*)(part + (long)s * 4096 * 1024 + base);
    acc4[0] += bf2f(p.x); acc4[1] += bf2f(p.y);
    acc4[2] += bf2f(p.z); acc4[3] += bf2f(p.w);
  }
  ushort4 o;
  o.x = f2bf(acc4[0] * inv);
  o.y = f2bf(acc4[1] * inv);
  o.z = f2bf(acc4[2] * inv);
  o.w = f2bf(acc4[3] * inv);
  *(ushort4*)(ob + b * 4096L * 1024 + base) = o;
}

// Fused prep: blocks [0,8192) cast x (fp32->bf16, float4); blocks
// [8192,12288) transpose+cast the 4 weight matrices (z = (blk-8192)>>10).
__global__ __launch_bounds__(256) void prep(
    const float* __restrict__ x, u16* __restrict__ xb,
    const float* __restrict__ W0, const float* __restrict__ W1,
    const float* __restrict__ W2, const float* __restrict__ W3,
    u16* __restrict__ O0, u16* __restrict__ O1,
    u16* __restrict__ O2, u16* __restrict__ O3)
{
  __shared__ float tile[32][33];
  int blk = blockIdx.x;
  if (blk < 8192) {
    int i = blk * 256 + threadIdx.x;      // 2M float4s
    float4 f = ((const float4*)x)[i];
    ushort4 o;
    o.x = f2bf(f.x); o.y = f2bf(f.y); o.z = f2bf(f.z); o.w = f2bf(f.w);
    ((ushort4*)xb)[i] = o;
  } else {
    blk -= 8192;
    const int z = blk >> 10, t = blk & 1023;
    const float* in = (z == 0) ? W0 : (z == 1) ? W1 : (z == 2) ? W2 : W3;
    u16* outp = (z == 0) ? O0 : (z == 1) ? O1 : (z == 2) ? O2 : O3;
    const int bx = (t & 31) * 32, by = (t >> 5) * 32;
    const int tx = threadIdx.x & 31, ty = threadIdx.x >> 5;   // 32 x 8
    for (int i = ty; i < 32; i += 8)
      tile[i][tx] = in[(long)(by + i) * 1024 + bx + tx];
    __syncthreads();
    for (int i = ty; i < 32; i += 8)
      outp[(long)(bx + i) * 1024 + by + tx] = f2bf(tile[tx][i]);
  }
}

extern "C" void kernel_launch(void* const* d_in, const int* in_sizes, int n_in,
                              void* d_out, int out_size, void* d_ws, size_t ws_size,
                              hipStream_t stream) {
  const float* x  = (const float*)d_in[0];
  const float* Wq = (const float*)d_in[1];
  const float* bq = (const float*)d_in[2];
  const float* Wk = (const float*)d_in[3];
  const float* bk = (const float*)d_in[4];
  const float* Wv = (const float*)d_in[5];
  const float* bv = (const float*)d_in[6];
  const float* Wo = (const float*)d_in[7];
  const float* bo = (const float*)d_in[8];
  float* out = (float*)d_out;

  const int B = 2, S = 4096, D = 1024;
  const long MS = (long)B * S;  // 8192
  const long MB = 1L << 20;

  // ---- workspace layout (top usage 152 MiB; ws_size >= 168 MiB proven) ----
  //  [0,16M)    qb  bf16 [8192,1024]   -- dead after QK_exp; reused as
  //                                       PV bf16 partials batch0 [2][4096][1024]
  //  [16,32M)   kb  bf16 [8192,1024]
  //  [32,48M)   vT  bf16 [B][1024][4096]
  //  [48,64M)   xb  bf16 [8192,1024]   -- aliased with ob (xb dead before PV)
  //  [64,72M)   WqkvT bf16 [3072,1024] + WoT bf16 [1024,1024]
  //  [72,136M)  probs bf16 [B][4096][4096]  (both batches)
  //  [136,152M) PV bf16 partials batch1 [2][4096][1024]
  // d_out (32MB fp32, dead until final proj) hosts lpartT [B][4096][64] fp32.
  char* w = (char*)d_ws;
  u16* qb  = (u16*)(w);
  u16* kb  = (u16*)(w + 16 * MB);
  u16* vT  = (u16*)(w + 32 * MB);
  u16* xb  = (u16*)(w + 48 * MB);
  u16* ob  = xb;                        // alias: xb dead before ob written
  u16* WqkvT = (u16*)(w + 64 * MB);
  u16* WoT = WqkvT + 3072L * 1024;
  u16* probs = (u16*)(w + 72 * MB);
  u16* partA = (u16*)(w);               // over qb, dead after QK_exp
  u16* partB = (u16*)(w + 136 * MB);
  float* lpartT = (float*)d_out;        // [2][4096][64] fp32 = 2MB

  // 1. fused prep: cast x + transpose/cast all 4 weights
  prep<<<dim3(8192 + 4096), 256, 0, stream>>>(
      x, xb, Wq, Wk, Wv, Wo,
      WqkvT, WqkvT + 1024L * 1024, WqkvT + 2048L * 1024, WoT);

  // 2. fused QKV projection: grid (24,64) = 1536 blocks (old engine)
  gemm_qkv<<<dim3(3 * D / 128, MS / 128), 256, 0, stream>>>(
      xb, WqkvT, qb, kb, vT, bq, bk, bv);

  // 3. attention, both batches per launch (new phased engine)
  const float scale = 0.125f;  // 1/sqrt(64)
  gemm_qk_exp<<<dim3(8, 64), 512, 0, stream>>>(
      qb, kb, probs, lpartT, scale);
  // qb now dead -> partA overlays it
  gemm_pv_splitk2<<<dim3(8, 32), 512, 0, stream>>>(
      probs, vT, partA, partB);
  reduce2_div_row<<<dim3(S, B), 256, 0, stream>>>(partA, partB, lpartT, ob);

  // 4. final projection -> fp32 d_out (overwrites lpartT scratch)
  gemm_bt<<<dim3(D / 128, MS / 128), 256, 0, stream>>>(ob, WoT, out, bo, D, D);
}

// Round 3
// 375.100 us; speedup vs baseline: 1.0936x; 1.0269x over previous
//
#include <hip/hip_runtime.h>

// bf16 stored as raw ushort everywhere; MFMA consumes __bf16 vectors.
typedef unsigned short u16;
using bf16x8  = __attribute__((ext_vector_type(8))) __bf16;
using floatx4 = __attribute__((ext_vector_type(4))) float;

__device__ __forceinline__ u16 f2bf(float f) {
  unsigned int u = __builtin_bit_cast(unsigned int, f);
  u += 0x7fffu + ((u >> 16) & 1u);          // round-to-nearest-even
  return (u16)(u >> 16);
}
__device__ __forceinline__ float bf2f(u16 h) {
  unsigned int u = ((unsigned int)h) << 16;
  return __builtin_bit_cast(float, u);
}

#define AS1(p) ((const __attribute__((address_space(1))) void*)(p))
#define AS3(p) ((__attribute__((address_space(3))) void*)(p))

// ================= OLD 128x128 engine (kept for bt only) ==================
#define GEMM_PROLOGUE_AT(bmv, bnv)                                           \
  __shared__ u16 As[128 * 32];                                               \
  __shared__ u16 Bs[128 * 32];                                               \
  const int tid  = threadIdx.x;                                              \
  const int wave = tid >> 6, lane = tid & 63;                                \
  const int wm = (wave >> 1) * 64, wn = (wave & 1) * 64;                     \
  const long bm = (bmv), bn = (bnv);                                         \
  floatx4 acc[4][4] = {};                                                    \
  const int srow = lane >> 2;                                                \
  const int scol = (lane & 3) * 8;                                           \
  const int c0 = wave * 2, c1 = c0 + 1;                                      \
  const int fr = lane & 15;                                                  \
  const int kq = (lane >> 4) * 8;                                            \
  const int oc = (lane >> 4) * 4;   /* swapped layout: col quad offset */

#define GEMM_PROLOGUE() GEMM_PROLOGUE_AT((long)blockIdx.y * 128, (long)blockIdx.x * 128)

#define GEMM_STAGE(Ab, Bb, K, k0)                                            \
    __syncthreads();                                                         \
    __builtin_amdgcn_global_load_lds(AS1(Ab + (long)(c0*16 + srow)*K + k0 + scol), AS3(As + c0*512), 16, 0, 0); \
    __builtin_amdgcn_global_load_lds(AS1(Ab + (long)(c1*16 + srow)*K + k0 + scol), AS3(As + c1*512), 16, 0, 0); \
    __builtin_amdgcn_global_load_lds(AS1(Bb + (long)(c0*16 + srow)*K + k0 + scol), AS3(Bs + c0*512), 16, 0, 0); \
    __builtin_amdgcn_global_load_lds(AS1(Bb + (long)(c1*16 + srow)*K + k0 + scol), AS3(Bs + c1*512), 16, 0, 0); \
    __syncthreads();                                                         \
    bf16x8 af[4], bfv[4];                                                    \
    _Pragma("unroll")                                                        \
    for (int mi = 0; mi < 4; ++mi)                                           \
      af[mi] = *(const bf16x8*)(As + (wm + mi*16 + fr)*32 + kq);             \
    _Pragma("unroll")                                                        \
    for (int ni = 0; ni < 4; ++ni)                                           \
      bfv[ni] = *(const bf16x8*)(Bs + (wn + ni*16 + fr)*32 + kq);

#define GEMM_KSTEP_SWAP(Ab, Bb, K, k0)                                       \
  {                                                                          \
    GEMM_STAGE(Ab, Bb, K, k0)                                                \
    _Pragma("unroll")                                                        \
    for (int mi = 0; mi < 4; ++mi)                                           \
      _Pragma("unroll")                                                      \
      for (int ni = 0; ni < 4; ++ni)                                         \
        acc[mi][ni] = __builtin_amdgcn_mfma_f32_16x16x32_bf16(bfv[ni], af[mi], acc[mi][ni], 0, 0, 0); \
  }

// ============ NEW 256x256 8-wave phased engine (BK=32, 4-slot ring) ========
// LDS ring: 4 slots x (A 16KB + B 16KB) = 128 KiB. Subtiled [16][16rows][32k]
// bf16 per operand-slot, st_16x32 XOR swizzle (byte ^= ((byte>>9)&1)<<5).
// Schedule per K-tile (2 phases of 16 MFMA): counted vmcnt(6) once per tile
// (tail 4 -> 0), stage units 5..6 ahead, slot overwritten >=2 phases after
// its last reader. T2 swizzle + T4 counted waits + T5 setprio.
#define NE_PROLOGUE(bmv, bnv)                                                \
  __shared__ u16 lds[65536];            /* 128 KiB */                        \
  const int tid = threadIdx.x;                                               \
  const int w = tid >> 6, lane = tid & 63;                                   \
  const int wm = (w >> 2) * 128, wn = (w & 3) * 64;                          \
  const int wm16 = (w >> 2) * 8;        /* A subtile base for this wave */   \
  const int wn4  = (w & 3) * 4;         /* B subtile base for this wave */   \
  const long bm = (bmv), bn = (bnv);                                         \
  floatx4 acc[8][4] = {};                                                    \
  const int fr = lane & 15;                                                  \
  const int kq = (lane >> 4) * 8;                                            \
  const int oc = (lane >> 4) * 4;                                            \
  /* staging: linear LDS dest (lane*16); source is inverse-swizzled */       \
  const int swz  = (lane * 16) ^ (((lane >> 5) & 1) << 5);                   \
  const int srow = swz >> 6;            /* [0,16) row within subtile */      \
  const int scol = (swz & 63) >> 1;     /* {0,8,16,24} k within tile */      \
  const int st0  = w * 2;               /* this wave's subtile pair */       \
  /* read-side swizzled byte offset within a subtile */                      \
  const int aoff = fr * 64 + ((kq * 2) ^ (((fr >> 3) & 1) << 5));

#define NE_SETUP_PTRS(Abp, Bbp, ldK)                                         \
  const u16* A0p = (Abp) + (long)(st0 * 16 + srow) * (ldK) + scol;           \
  const u16* A1p = A0p + 16L * (ldK);                                        \
  const u16* B0p = (Bbp) + (long)(st0 * 16 + srow) * (ldK) + scol;           \
  const u16* B1p = B0p + 16L * (ldK);

#define NE_SA(T)                                                             \
  { u16* d_ = lds + (((T) & 3) * 16384) + st0 * 512;                         \
    long o_ = (long)(T) * 32;                                                \
    __builtin_amdgcn_global_load_lds(AS1(A0p + o_), AS3(d_), 16, 0, 0);      \
    __builtin_amdgcn_global_load_lds(AS1(A1p + o_), AS3(d_ + 512), 16, 0, 0); }
#define NE_SB(T)                                                             \
  { u16* d_ = lds + (((T) & 3) * 16384) + 8192 + st0 * 512;                  \
    long o_ = (long)(T) * 32;                                                \
    __builtin_amdgcn_global_load_lds(AS1(B0p + o_), AS3(d_), 16, 0, 0);      \
    __builtin_amdgcn_global_load_lds(AS1(B1p + o_), AS3(d_ + 512), 16, 0, 0); }

// One K-tile = 2 phases. Phase0: read A(lo)+B, stage B(T+2), 16 MFMA.
// Phase1: read A(hi), stage A(T+3), 16 MFMA, counted vmcnt, barrier.
// MFMA operand order: MF(af_i, bf_i) -> NS (lane&15 = n-col) or
// swapped (lane&15 = m-row) via the wrapper macros below.
#define NE_TILE_G(T, NT, MF)                                                 \
  {                                                                          \
    const char* sb_ = (const char*)lds + ((T) & 3) * 32768;                  \
    bf16x8 af[4], bf[4];                                                     \
    _Pragma("unroll")                                                        \
    for (int i = 0; i < 4; ++i)                                              \
      af[i] = *(const bf16x8*)(sb_ + (wm16 + i) * 1024 + aoff);              \
    _Pragma("unroll")                                                        \
    for (int i = 0; i < 4; ++i)                                              \
      bf[i] = *(const bf16x8*)(sb_ + 16384 + (wn4 + i) * 1024 + aoff);       \
    if ((T) + 2 < (NT)) NE_SB((T) + 2)                                       \
    __builtin_amdgcn_s_barrier();                                            \
    asm volatile("s_waitcnt lgkmcnt(0)" ::: "memory");                       \
    __builtin_amdgcn_sched_barrier(0);                                       \
    __builtin_amdgcn_s_setprio(1);                                           \
    _Pragma("unroll")                                                        \
    for (int mi = 0; mi < 4; ++mi)                                           \
      _Pragma("unroll")                                                      \
      for (int ni = 0; ni < 4; ++ni)                                         \
        acc[mi][ni] = MF(mi, ni, acc[mi][ni]);                               \
    __builtin_amdgcn_s_setprio(0);                                           \
    __builtin_amdgcn_s_barrier();                                            \
    __builtin_amdgcn_sched_barrier(0);                                       \
    _Pragma("unroll")                                                        \
    for (int i = 0; i < 4; ++i)                                              \
      af[i] = *(const bf16x8*)(sb_ + (wm16 + 4 + i) * 1024 + aoff);          \
    if ((T) + 3 < (NT)) NE_SA((T) + 3)                                       \
    __builtin_amdgcn_s_barrier();                                            \
    asm volatile("s_waitcnt lgkmcnt(0)" ::: "memory");                       \
    __builtin_amdgcn_sched_barrier(0);                                       \
    __builtin_amdgcn_s_setprio(1);                                           \
    _Pragma("unroll")                                                        \
    for (int mi = 0; mi < 4; ++mi)                                           \
      _Pragma("unroll")                                                      \
      for (int ni = 0; ni < 4; ++ni)                                         \
        acc[4 + mi][ni] = MF(mi, ni, acc[4 + mi][ni]);                       \
    __builtin_amdgcn_s_setprio(0);                                           \
    if ((T) < (NT) - 3)       { asm volatile("s_waitcnt vmcnt(6)" ::: "memory"); } \
    else if ((T) == (NT) - 3) { asm volatile("s_waitcnt vmcnt(4)" ::: "memory"); } \
    else if ((T) == (NT) - 2) { asm volatile("s_waitcnt vmcnt(0)" ::: "memory"); } \
    __builtin_amdgcn_s_barrier();                                            \
    __builtin_amdgcn_sched_barrier(0);                                       \
  }

#define NE_MF_SWAP(mi, ni, c) __builtin_amdgcn_mfma_f32_16x16x32_bf16(bf[ni], af[mi], (c), 0, 0, 0)
#define NE_MF_NS(mi, ni, c)   __builtin_amdgcn_mfma_f32_16x16x32_bf16(af[mi], bf[ni], (c), 0, 0, 0)
#define NE_TILE(T, NT)    NE_TILE_G(T, NT, NE_MF_SWAP)
#define NE_TILE_NS(T, NT) NE_TILE_G(T, NT, NE_MF_NS)

#define NE_START()                                                           \
  NE_SA(0) NE_SB(0) NE_SA(1) NE_SB(1) NE_SA(2)                               \
  asm volatile("s_waitcnt vmcnt(6)" ::: "memory");                           \
  __builtin_amdgcn_s_barrier();                                              \
  __builtin_amdgcn_sched_barrier(0);

// Final projection: C = A*Bt^T + bias, fp32 out, swapped epilogue (float4).
__global__ __launch_bounds__(256) void gemm_bt(
    const u16* __restrict__ A, const u16* __restrict__ Bt,
    float* __restrict__ Cout, const float* __restrict__ bias, int N, int K)
{
  GEMM_PROLOGUE();
  const u16* Ab = A + bm * K;
  const u16* Bb = Bt + bn * K;
  for (int k0 = 0; k0 < K; k0 += 32) GEMM_KSTEP_SWAP(Ab, Bb, K, k0);

#pragma unroll
  for (int mi = 0; mi < 4; ++mi) {
    long row = bm + wm + mi*16 + fr;
#pragma unroll
    for (int ni = 0; ni < 4; ++ni) {
      long colb = bn + wn + ni*16 + oc;
      float4 bv4 = *(const float4*)(bias + colb);
      float4 o;
      o.x = acc[mi][ni][0] + bv4.x;
      o.y = acc[mi][ni][1] + bv4.y;
      o.z = acc[mi][ni][2] + bv4.z;
      o.w = acc[mi][ni][3] + bv4.w;
      *(float4*)(Cout + row * N + colb) = o;
    }
  }
}

// Batch-combined QK^T + unnormalized exp — phased 256^2 engine.
// Grid (8,64) = 512 blocks x 512 thr. xcd = blockIdx.x; b = xcd>>2; each XCD
// owns a 4-row by-band of one batch. P[b] = exp(scale*q k^T) bf16;
// lpartT[b][row][64] fp32 (64-col group partial rowsums).
__global__ __launch_bounds__(512, 2) void gemm_qk_exp(
    const u16* __restrict__ q, const u16* __restrict__ k,
    u16* __restrict__ probs, float* __restrict__ lpartT, float alpha)
{
  const int N = 4096;
  const int xcd = blockIdx.x;
  const int j = blockIdx.y;
  const long b = xcd >> 2;
  const int by = (xcd & 3) * 4 + (j & 3);   // [0,16)
  const int bx = j >> 2;                    // [0,16)

  NE_PROLOGUE((long)by * 256, (long)bx * 256);
  const u16* Ab = q + b * 4096 * 1024 + bm * 1024;
  const u16* Bb = k + b * 4096 * 1024 + bn * 1024;
  NE_SETUP_PTRS(Ab, Bb, 1024);
  u16* P = probs + b * 4096L * 4096;
  float* lp = lpartT + b * 4096 * 64;

  NE_START()
  for (int T = 0; T < 32; ++T) NE_TILE(T, 32)

  const float a2 = alpha * 1.44269504f;     // exp(x*alpha) = exp2(x*a2)
  const int cg = bx * 4 + (w & 3);          // 64-col group index
#pragma unroll
  for (int mi = 0; mi < 8; ++mi) {
    long row = bm + wm + mi * 16 + fr;
    float rs = 0.f;
#pragma unroll
    for (int ni = 0; ni < 4; ++ni) {
      long colb = bn + wn + ni * 16 + oc;
      float e0 = __builtin_amdgcn_exp2f(acc[mi][ni][0] * a2);
      float e1 = __builtin_amdgcn_exp2f(acc[mi][ni][1] * a2);
      float e2 = __builtin_amdgcn_exp2f(acc[mi][ni][2] * a2);
      float e3 = __builtin_amdgcn_exp2f(acc[mi][ni][3] * a2);
      rs += (e0 + e1) + (e2 + e3);
      ushort4 o;
      o.x = f2bf(e0); o.y = f2bf(e1); o.z = f2bf(e2); o.w = f2bf(e3);
      *(ushort4*)(P + row * N + colb) = o;
    }
    rs += __shfl_xor(rs, 16);
    rs += __shfl_xor(rs, 32);
    if (lane < 16)
      lp[(bm + wm + mi * 16 + lane) * 64 + cg] = rs;
  }
}

// Batch-combined PV, split-K=2 — phased 256^2 engine.
// Grid (8,32) = 256 blocks x 512 thr = exactly 1 block/CU, one full round.
__global__ __launch_bounds__(512, 2) void gemm_pv_splitk2(
    const u16* __restrict__ probs, const u16* __restrict__ vT,
    u16* __restrict__ pA, u16* __restrict__ pB)
{
  const int xcd = blockIdx.x;
  const int j = blockIdx.y;
  const long b = xcd >> 2;
  const int sp = (xcd >> 1) & 1;
  const int by = (xcd & 1) * 8 + (j & 7);   // [0,16)
  const int bx = j >> 3;                    // [0,4)

  NE_PROLOGUE((long)by * 256, (long)bx * 256);
  const u16* Ab = probs + b * 4096L * 4096 + bm * 4096 + sp * 2048;
  const u16* Bb = vT + b * 1024L * 4096 + bn * 4096 + sp * 2048;
  NE_SETUP_PTRS(Ab, Bb, 4096);
  u16* part = (b ? pB : pA) + (long)sp * 4096 * 1024;

  NE_START()
  for (int T = 0; T < 64; ++T) NE_TILE(T, 64)

#pragma unroll
  for (int mi = 0; mi < 8; ++mi) {
    long row = bm + wm + mi * 16 + fr;
#pragma unroll
    for (int ni = 0; ni < 4; ++ni) {
      long colb = bn + wn + ni * 16 + oc;
      ushort4 o;
      o.x = f2bf(acc[mi][ni][0]);
      o.y = f2bf(acc[mi][ni][1]);
      o.z = f2bf(acc[mi][ni][2]);
      o.w = f2bf(acc[mi][ni][3]);
      *(ushort4*)(part + row * 1024 + colb) = o;
    }
  }
}

// Fused QKV projection — phased 256^2 engine. A=xb [8192,1024],
// Bt=WqkvT [3072,1024]. Grid (8,48) = 384 blocks x 512 thr (1.5 rounds).
// xcd = blockIdx.x owns A-rows [xcd*1024, +1024) (2MB, L2-resident) and
// sweeps 12 n-tiles m-fastest. Block-uniform: bx<8 -> q/k (swapped epi,
// ushort4 along d); bx>=8 -> v (non-swapped epi, ushort4 along s into vT).
__global__ __launch_bounds__(512, 2) void gemm_qkv(
    const u16* __restrict__ A, const u16* __restrict__ Bt,
    u16* __restrict__ qb, u16* __restrict__ kb, u16* __restrict__ vT,
    const float* __restrict__ bq, const float* __restrict__ bk,
    const float* __restrict__ bv)
{
  const int xcd = blockIdx.x;
  const int j = blockIdx.y;                 // [0,48)
  const int by = xcd * 4 + (j & 3);         // [0,32)
  const int bx = j >> 2;                    // [0,12)

  NE_PROLOGUE((long)by * 256, (long)bx * 256);
  const u16* Ab = A + bm * 1024;
  const u16* Bb = Bt + bn * 1024;
  NE_SETUP_PTRS(Ab, Bb, 1024);

  if (bn < 2048) {
    NE_START()
    for (int T = 0; T < 32; ++T) NE_TILE(T, 32)
    u16* C = (bn < 1024) ? qb : kb;
    const float* bias = (bn < 1024) ? bq : bk;
#pragma unroll
    for (int mi = 0; mi < 8; ++mi) {
      long row = bm + wm + mi * 16 + fr;
#pragma unroll
      for (int ni = 0; ni < 4; ++ni) {
        long colg = bn + wn + ni * 16 + oc;
        long cc = colg & 1023;
        float4 bv4 = *(const float4*)(bias + cc);
        ushort4 o;
        o.x = f2bf(acc[mi][ni][0] + bv4.x);
        o.y = f2bf(acc[mi][ni][1] + bv4.y);
        o.z = f2bf(acc[mi][ni][2] + bv4.z);
        o.w = f2bf(acc[mi][ni][3] + bv4.w);
        *(ushort4*)(C + row * 1024 + cc) = o;
      }
    }
  } else {
    NE_START()
    for (int T = 0; T < 32; ++T) NE_TILE_NS(T, 32)
    const int orow = (lane >> 4) * 4;       // non-swapped: 4 consecutive rows
    const long b_ = bm >> 12;               // block entirely in one batch
    const long s0 = (bm & 4095) + wm;
    u16* vb = vT + b_ * (1024L * 4096);
#pragma unroll
    for (int ni = 0; ni < 4; ++ni) {
      long d = bn + wn + ni * 16 + fr - 2048;
      float bvv = bv[d];
#pragma unroll
      for (int mi = 0; mi < 8; ++mi) {
        long s = s0 + mi * 16 + orow;
        ushort4 o;
        o.x = f2bf(acc[mi][ni][0] + bvv);
        o.y = f2bf(acc[mi][ni][1] + bvv);
        o.z = f2bf(acc[mi][ni][2] + bvv);
        o.w = f2bf(acc[mi][ni][3] + bvv);
        *(ushort4*)(vb + d * 4096L + s) = o;
      }
    }
  }
}

// Combined reduce + softmax-normalize: grid (4096 rows, 2 batches).
__global__ __launch_bounds__(256) void reduce2_div_row(
    const u16* __restrict__ pA, const u16* __restrict__ pB,
    const float* __restrict__ lpartT, u16* __restrict__ ob)
{
  const int row = blockIdx.x;           // [0,4096)
  const long b = blockIdx.y;
  const int tid = threadIdx.x;
  const u16* part = b ? pB : pA;
  const float* lp = lpartT + b * 4096 * 64;
  __shared__ float sl;
  if (tid < 64) {
    float s = lp[(long)row * 64 + tid];
#pragma unroll
    for (int off = 32; off; off >>= 1) s += __shfl_down(s, off);
    if (tid == 0) sl = s;
  }
  __syncthreads();
  const float inv = 1.0f / sl;
  const long base = (long)row * 1024 + tid * 4;
  float acc4[4] = {0.f, 0.f, 0.f, 0.f};
#pragma unroll
  for (int s = 0; s < 2; ++s) {
    ushort4 p = *(const ushort4*)(part + (long)s * 4096 * 1024 + base);
    acc4[0] += bf2f(p.x); acc4[1] += bf2f(p.y);
    acc4[2] += bf2f(p.z); acc4[3] += bf2f(p.w);
  }
  ushort4 o;
  o.x = f2bf(acc4[0] * inv);
  o.y = f2bf(acc4[1] * inv);
  o.z = f2bf(acc4[2] * inv);
  o.w = f2bf(acc4[3] * inv);
  *(ushort4*)(ob + b * 4096L * 1024 + base) = o;
}

// Fused prep: blocks [0,8192) cast x (fp32->bf16, float4); blocks
// [8192,12288) transpose+cast the 4 weight matrices (z = (blk-8192)>>10).
__global__ __launch_bounds__(256) void prep(
    const float* __restrict__ x, u16* __restrict__ xb,
    const float* __restrict__ W0, const float* __restrict__ W1,
    const float* __restrict__ W2, const float* __restrict__ W3,
    u16* __restrict__ O0, u16* __restrict__ O1,
    u16* __restrict__ O2, u16* __restrict__ O3)
{
  __shared__ float tile[32][33];
  int blk = blockIdx.x;
  if (blk < 8192) {
    int i = blk * 256 + threadIdx.x;      // 2M float4s
    float4 f = ((const float4*)x)[i];
    ushort4 o;
    o.x = f2bf(f.x); o.y = f2bf(f.y); o.z = f2bf(f.z); o.w = f2bf(f.w);
    ((ushort4*)xb)[i] = o;
  } else {
    blk -= 8192;
    const int z = blk >> 10, t = blk & 1023;
    const float* in = (z == 0) ? W0 : (z == 1) ? W1 : (z == 2) ? W2 : W3;
    u16* outp = (z == 0) ? O0 : (z == 1) ? O1 : (z == 2) ? O2 : O3;
    const int bx = (t & 31) * 32, by = (t >> 5) * 32;
    const int tx = threadIdx.x & 31, ty = threadIdx.x >> 5;   // 32 x 8
    for (int i = ty; i < 32; i += 8)
      tile[i][tx] = in[(long)(by + i) * 1024 + bx + tx];
    __syncthreads();
    for (int i = ty; i < 32; i += 8)
      outp[(long)(bx + i) * 1024 + by + tx] = f2bf(tile[tx][i]);
  }
}

extern "C" void kernel_launch(void* const* d_in, const int* in_sizes, int n_in,
                              void* d_out, int out_size, void* d_ws, size_t ws_size,
                              hipStream_t stream) {
  const float* x  = (const float*)d_in[0];
  const float* Wq = (const float*)d_in[1];
  const float* bq = (const float*)d_in[2];
  const float* Wk = (const float*)d_in[3];
  const float* bk = (const float*)d_in[4];
  const float* Wv = (const float*)d_in[5];
  const float* bv = (const float*)d_in[6];
  const float* Wo = (const float*)d_in[7];
  const float* bo = (const float*)d_in[8];
  float* out = (float*)d_out;

  const int B = 2, S = 4096, D = 1024;
  const long MS = (long)B * S;  // 8192
  const long MB = 1L << 20;

  // ---- workspace layout (top usage 152 MiB; ws_size >= 168 MiB proven) ----
  //  [0,16M)    qb  bf16 [8192,1024]   -- dead after QK_exp; reused as
  //                                       PV bf16 partials batch0 [2][4096][1024]
  //  [16,32M)   kb  bf16 [8192,1024]
  //  [32,48M)   vT  bf16 [B][1024][4096]
  //  [48,64M)   xb  bf16 [8192,1024]   -- aliased with ob (xb dead before PV)
  //  [64,72M)   WqkvT bf16 [3072,1024] + WoT bf16 [1024,1024]
  //  [72,136M)  probs bf16 [B][4096][4096]  (both batches)
  //  [136,152M) PV bf16 partials batch1 [2][4096][1024]
  // d_out (32MB fp32, dead until final proj) hosts lpartT [B][4096][64] fp32.
  char* w = (char*)d_ws;
  u16* qb  = (u16*)(w);
  u16* kb  = (u16*)(w + 16 * MB);
  u16* vT  = (u16*)(w + 32 * MB);
  u16* xb  = (u16*)(w + 48 * MB);
  u16* ob  = xb;                        // alias: xb dead before ob written
  u16* WqkvT = (u16*)(w + 64 * MB);
  u16* WoT = WqkvT + 3072L * 1024;
  u16* probs = (u16*)(w + 72 * MB);
  u16* partA = (u16*)(w);               // over qb, dead after QK_exp
  u16* partB = (u16*)(w + 136 * MB);
  float* lpartT = (float*)d_out;        // [2][4096][64] fp32 = 2MB

  // 1. fused prep: cast x + transpose/cast all 4 weights
  prep<<<dim3(8192 + 4096), 256, 0, stream>>>(
      x, xb, Wq, Wk, Wv, Wo,
      WqkvT, WqkvT + 1024L * 1024, WqkvT + 2048L * 1024, WoT);

  // 2. fused QKV projection: grid (8,48) = 384 blocks (new engine)
  gemm_qkv<<<dim3(8, 48), 512, 0, stream>>>(
      xb, WqkvT, qb, kb, vT, bq, bk, bv);

  // 3. attention, both batches per launch (new phased engine)
  const float scale = 0.125f;  // 1/sqrt(64)
  gemm_qk_exp<<<dim3(8, 64), 512, 0, stream>>>(
      qb, kb, probs, lpartT, scale);
  // qb now dead -> partA overlays it
  gemm_pv_splitk2<<<dim3(8, 32), 512, 0, stream>>>(
      probs, vT, partA, partB);
  reduce2_div_row<<<dim3(S, B), 256, 0, stream>>>(partA, partB, lpartT, ob);

  // 4. final projection -> fp32 d_out (overwrites lpartT scratch)
  gemm_bt<<<dim3(D / 128, MS / 128), 256, 0, stream>>>(ob, WoT, out, bo, D, D);
}

// Round 4
// 368.996 us; speedup vs baseline: 1.1116x; 1.0165x over previous
//
#include <hip/hip_runtime.h>

// bf16 stored as raw ushort everywhere; MFMA consumes __bf16 vectors.
typedef unsigned short u16;
using bf16x8  = __attribute__((ext_vector_type(8))) __bf16;
using floatx4 = __attribute__((ext_vector_type(4))) float;

__device__ __forceinline__ u16 f2bf(float f) {
  unsigned int u = __builtin_bit_cast(unsigned int, f);
  u += 0x7fffu + ((u >> 16) & 1u);          // round-to-nearest-even
  return (u16)(u >> 16);
}
__device__ __forceinline__ float bf2f(u16 h) {
  unsigned int u = ((unsigned int)h) << 16;
  return __builtin_bit_cast(float, u);
}

#define AS1(p) ((const __attribute__((address_space(1))) void*)(p))
#define AS3(p) ((__attribute__((address_space(3))) void*)(p))

// ================= OLD 128x128 engine (kept for bt only) ==================
#define GEMM_PROLOGUE_AT(bmv, bnv)                                           \
  __shared__ u16 As[128 * 32];                                               \
  __shared__ u16 Bs[128 * 32];                                               \
  const int tid  = threadIdx.x;                                              \
  const int wave = tid >> 6, lane = tid & 63;                                \
  const int wm = (wave >> 1) * 64, wn = (wave & 1) * 64;                     \
  const long bm = (bmv), bn = (bnv);                                         \
  floatx4 acc[4][4] = {};                                                    \
  const int srow = lane >> 2;                                                \
  const int scol = (lane & 3) * 8;                                           \
  const int c0 = wave * 2, c1 = c0 + 1;                                      \
  const int fr = lane & 15;                                                  \
  const int kq = (lane >> 4) * 8;                                            \
  const int oc = (lane >> 4) * 4;   /* swapped layout: col quad offset */

#define GEMM_PROLOGUE() GEMM_PROLOGUE_AT((long)blockIdx.y * 128, (long)blockIdx.x * 128)

#define GEMM_STAGE(Ab, Bb, K, k0)                                            \
    __syncthreads();                                                         \
    __builtin_amdgcn_global_load_lds(AS1(Ab + (long)(c0*16 + srow)*K + k0 + scol), AS3(As + c0*512), 16, 0, 0); \
    __builtin_amdgcn_global_load_lds(AS1(Ab + (long)(c1*16 + srow)*K + k0 + scol), AS3(As + c1*512), 16, 0, 0); \
    __builtin_amdgcn_global_load_lds(AS1(Bb + (long)(c0*16 + srow)*K + k0 + scol), AS3(Bs + c0*512), 16, 0, 0); \
    __builtin_amdgcn_global_load_lds(AS1(Bb + (long)(c1*16 + srow)*K + k0 + scol), AS3(Bs + c1*512), 16, 0, 0); \
    __syncthreads();                                                         \
    bf16x8 af[4], bfv[4];                                                    \
    _Pragma("unroll")                                                        \
    for (int mi = 0; mi < 4; ++mi)                                           \
      af[mi] = *(const bf16x8*)(As + (wm + mi*16 + fr)*32 + kq);             \
    _Pragma("unroll")                                                        \
    for (int ni = 0; ni < 4; ++ni)                                           \
      bfv[ni] = *(const bf16x8*)(Bs + (wn + ni*16 + fr)*32 + kq);

#define GEMM_KSTEP_SWAP(Ab, Bb, K, k0)                                       \
  {                                                                          \
    GEMM_STAGE(Ab, Bb, K, k0)                                                \
    _Pragma("unroll")                                                        \
    for (int mi = 0; mi < 4; ++mi)                                           \
      _Pragma("unroll")                                                      \
      for (int ni = 0; ni < 4; ++ni)                                         \
        acc[mi][ni] = __builtin_amdgcn_mfma_f32_16x16x32_bf16(bfv[ni], af[mi], acc[mi][ni], 0, 0, 0); \
  }

// ============ NEW 256x256 8-wave phased engine (BK=32, 4-slot ring) ========
// LDS ring: 4 slots x (A 16KB + B 16KB) = 128 KiB. Subtiled [16][16rows][32k]
// bf16 per operand-slot, st_16x32 XOR swizzle (byte ^= ((byte>>9)&1)<<5).
// R3 lesson: 4 barriers/tile = lockstep, MfmaUtil 31%. Correctness needs only
// ONE barrier + per-wave counted vmcnt per tile (all LDS writes are
// global_load_lds into ring slots >=2 ahead of the read slot; each wave's
// vmcnt(6) retires its own loads through tile T+1; the single barrier makes
// that collective). Fewer barriers -> wave drift -> T5 setprio role-split.
#define NE_PROLOGUE(bmv, bnv)                                                \
  __shared__ u16 lds[65536];            /* 128 KiB */                        \
  const int tid = threadIdx.x;                                               \
  const int w = tid >> 6, lane = tid & 63;                                   \
  const int wm = (w >> 2) * 128, wn = (w & 3) * 64;                          \
  const int wm16 = (w >> 2) * 8;        /* A subtile base for this wave */   \
  const int wn4  = (w & 3) * 4;         /* B subtile base for this wave */   \
  const long bm = (bmv), bn = (bnv);                                         \
  floatx4 acc[8][4] = {};                                                    \
  const int fr = lane & 15;                                                  \
  const int kq = (lane >> 4) * 8;                                            \
  const int oc = (lane >> 4) * 4;                                            \
  /* staging: linear LDS dest (lane*16); source is inverse-swizzled */       \
  const int swz  = (lane * 16) ^ (((lane >> 5) & 1) << 5);                   \
  const int srow = swz >> 6;            /* [0,16) row within subtile */      \
  const int scol = (swz & 63) >> 1;     /* {0,8,16,24} k within tile */      \
  const int st0  = w * 2;               /* this wave's subtile pair */       \
  /* read-side swizzled byte offset within a subtile */                      \
  const int aoff = fr * 64 + ((kq * 2) ^ (((fr >> 3) & 1) << 5));

#define NE_SETUP_PTRS(Abp, Bbp, ldK)                                         \
  const u16* A0p = (Abp) + (long)(st0 * 16 + srow) * (ldK) + scol;           \
  const u16* A1p = A0p + 16L * (ldK);                                        \
  const u16* B0p = (Bbp) + (long)(st0 * 16 + srow) * (ldK) + scol;           \
  const u16* B1p = B0p + 16L * (ldK);

#define NE_SA(T)                                                             \
  { u16* d_ = lds + (((T) & 3) * 16384) + st0 * 512;                         \
    long o_ = (long)(T) * 32;                                                \
    __builtin_amdgcn_global_load_lds(AS1(A0p + o_), AS3(d_), 16, 0, 0);      \
    __builtin_amdgcn_global_load_lds(AS1(A1p + o_), AS3(d_ + 512), 16, 0, 0); }
#define NE_SB(T)                                                             \
  { u16* d_ = lds + (((T) & 3) * 16384) + 8192 + st0 * 512;                  \
    long o_ = (long)(T) * 32;                                                \
    __builtin_amdgcn_global_load_lds(AS1(B0p + o_), AS3(d_), 16, 0, 0);      \
    __builtin_amdgcn_global_load_lds(AS1(B1p + o_), AS3(d_ + 512), 16, 0, 0); }

// One K-tile, single-barrier schedule:
//   issue stage {B(T+2), A(T+3)}  (slots disjoint from read slot T&3)
//   lo ds_reads -> lgkm(0)+SGB -> 16 MFMA   (acc[0..3])
//   hi ds_reads -> lgkm(0)+SGB -> 16 MFMA   (acc[4..7])
//   counted vmcnt (6 / tail 4,0) -> s_barrier
// Steady-state outstanding at the wait = {A,B}(T+2) + A(T+3) = 6.
#define NE_TILE_G(T, NT, MF)                                                 \
  {                                                                          \
    const char* sb_ = (const char*)lds + ((T) & 3) * 32768;                  \
    if ((T) + 2 < (NT)) NE_SB((T) + 2)                                       \
    if ((T) + 3 < (NT)) NE_SA((T) + 3)                                       \
    bf16x8 af[4], bf[4];                                                     \
    _Pragma("unroll")                                                        \
    for (int i = 0; i < 4; ++i)                                              \
      af[i] = *(const bf16x8*)(sb_ + (wm16 + i) * 1024 + aoff);              \
    _Pragma("unroll")                                                        \
    for (int i = 0; i < 4; ++i)                                              \
      bf[i] = *(const bf16x8*)(sb_ + 16384 + (wn4 + i) * 1024 + aoff);       \
    asm volatile("s_waitcnt lgkmcnt(0)" ::: "memory");                       \
    __builtin_amdgcn_sched_barrier(0);                                       \
    __builtin_amdgcn_s_setprio(1);                                           \
    _Pragma("unroll")                                                        \
    for (int mi = 0; mi < 4; ++mi)                                           \
      _Pragma("unroll")                                                      \
      for (int ni = 0; ni < 4; ++ni)                                         \
        acc[mi][ni] = MF(mi, ni, acc[mi][ni]);                               \
    __builtin_amdgcn_s_setprio(0);                                           \
    _Pragma("unroll")                                                        \
    for (int i = 0; i < 4; ++i)                                              \
      af[i] = *(const bf16x8*)(sb_ + (wm16 + 4 + i) * 1024 + aoff);          \
    asm volatile("s_waitcnt lgkmcnt(0)" ::: "memory");                       \
    __builtin_amdgcn_sched_barrier(0);                                       \
    __builtin_amdgcn_s_setprio(1);                                           \
    _Pragma("unroll")                                                        \
    for (int mi = 0; mi < 4; ++mi)                                           \
      _Pragma("unroll")                                                      \
      for (int ni = 0; ni < 4; ++ni)                                         \
        acc[4 + mi][ni] = MF(mi, ni, acc[4 + mi][ni]);                       \
    __builtin_amdgcn_s_setprio(0);                                           \
    if ((T) < (NT) - 3)       { asm volatile("s_waitcnt vmcnt(6)" ::: "memory"); } \
    else if ((T) == (NT) - 3) { asm volatile("s_waitcnt vmcnt(4)" ::: "memory"); } \
    else if ((T) == (NT) - 2) { asm volatile("s_waitcnt vmcnt(0)" ::: "memory"); } \
    __builtin_amdgcn_s_barrier();                                            \
    __builtin_amdgcn_sched_barrier(0);                                       \
  }

#define NE_MF_SWAP(mi, ni, c) __builtin_amdgcn_mfma_f32_16x16x32_bf16(bf[ni], af[mi], (c), 0, 0, 0)
#define NE_MF_NS(mi, ni, c)   __builtin_amdgcn_mfma_f32_16x16x32_bf16(af[mi], bf[ni], (c), 0, 0, 0)
#define NE_TILE(T, NT)    NE_TILE_G(T, NT, NE_MF_SWAP)
#define NE_TILE_NS(T, NT) NE_TILE_G(T, NT, NE_MF_NS)

#define NE_START()                                                           \
  NE_SA(0) NE_SB(0) NE_SA(1) NE_SB(1) NE_SA(2)                               \
  asm volatile("s_waitcnt vmcnt(6)" ::: "memory");                           \
  __builtin_amdgcn_s_barrier();                                              \
  __builtin_amdgcn_sched_barrier(0);

// Final projection: C = A*Bt^T + bias, fp32 out, swapped epilogue (float4).
__global__ __launch_bounds__(256) void gemm_bt(
    const u16* __restrict__ A, const u16* __restrict__ Bt,
    float* __restrict__ Cout, const float* __restrict__ bias, int N, int K)
{
  GEMM_PROLOGUE();
  const u16* Ab = A + bm * K;
  const u16* Bb = Bt + bn * K;
  for (int k0 = 0; k0 < K; k0 += 32) GEMM_KSTEP_SWAP(Ab, Bb, K, k0);

#pragma unroll
  for (int mi = 0; mi < 4; ++mi) {
    long row = bm + wm + mi*16 + fr;
#pragma unroll
    for (int ni = 0; ni < 4; ++ni) {
      long colb = bn + wn + ni*16 + oc;
      float4 bv4 = *(const float4*)(bias + colb);
      float4 o;
      o.x = acc[mi][ni][0] + bv4.x;
      o.y = acc[mi][ni][1] + bv4.y;
      o.z = acc[mi][ni][2] + bv4.z;
      o.w = acc[mi][ni][3] + bv4.w;
      *(float4*)(Cout + row * N + colb) = o;
    }
  }
}

// Batch-combined QK^T + unnormalized exp — phased 256^2 engine.
// Grid (8,64) = 512 blocks x 512 thr. xcd = blockIdx.x; b = xcd>>2; each XCD
// owns a 4-row by-band of one batch. P[b] = exp(scale*q k^T) bf16;
// lpartT[b][row][64] fp32 (64-col group partial rowsums).
__global__ __launch_bounds__(512, 2) void gemm_qk_exp(
    const u16* __restrict__ q, const u16* __restrict__ k,
    u16* __restrict__ probs, float* __restrict__ lpartT, float alpha)
{
  const int N = 4096;
  const int xcd = blockIdx.x;
  const int j = blockIdx.y;
  const long b = xcd >> 2;
  const int by = (xcd & 3) * 4 + (j & 3);   // [0,16)
  const int bx = j >> 2;                    // [0,16)

  NE_PROLOGUE((long)by * 256, (long)bx * 256);
  const u16* Ab = q + b * 4096 * 1024 + bm * 1024;
  const u16* Bb = k + b * 4096 * 1024 + bn * 1024;
  NE_SETUP_PTRS(Ab, Bb, 1024);
  u16* P = probs + b * 4096L * 4096;
  float* lp = lpartT + b * 4096 * 64;

  NE_START()
  for (int T = 0; T < 32; ++T) NE_TILE(T, 32)

  const float a2 = alpha * 1.44269504f;     // exp(x*alpha) = exp2(x*a2)
  const int cg = bx * 4 + (w & 3);          // 64-col group index
#pragma unroll
  for (int mi = 0; mi < 8; ++mi) {
    long row = bm + wm + mi * 16 + fr;
    float rs = 0.f;
#pragma unroll
    for (int ni = 0; ni < 4; ++ni) {
      long colb = bn + wn + ni * 16 + oc;
      float e0 = __builtin_amdgcn_exp2f(acc[mi][ni][0] * a2);
      float e1 = __builtin_amdgcn_exp2f(acc[mi][ni][1] * a2);
      float e2 = __builtin_amdgcn_exp2f(acc[mi][ni][2] * a2);
      float e3 = __builtin_amdgcn_exp2f(acc[mi][ni][3] * a2);
      rs += (e0 + e1) + (e2 + e3);
      ushort4 o;
      o.x = f2bf(e0); o.y = f2bf(e1); o.z = f2bf(e2); o.w = f2bf(e3);
      *(ushort4*)(P + row * N + colb) = o;
    }
    rs += __shfl_xor(rs, 16);
    rs += __shfl_xor(rs, 32);
    if (lane < 16)
      lp[(bm + wm + mi * 16 + lane) * 64 + cg] = rs;
  }
}

// Batch-combined PV, split-K=2 — phased 256^2 engine.
// Grid (8,32) = 256 blocks x 512 thr = exactly 1 block/CU, one full round.
__global__ __launch_bounds__(512, 2) void gemm_pv_splitk2(
    const u16* __restrict__ probs, const u16* __restrict__ vT,
    u16* __restrict__ pA, u16* __restrict__ pB)
{
  const int xcd = blockIdx.x;
  const int j = blockIdx.y;
  const long b = xcd >> 2;
  const int sp = (xcd >> 1) & 1;
  const int by = (xcd & 1) * 8 + (j & 7);   // [0,16)
  const int bx = j >> 3;                    // [0,4)

  NE_PROLOGUE((long)by * 256, (long)bx * 256);
  const u16* Ab = probs + b * 4096L * 4096 + bm * 4096 + sp * 2048;
  const u16* Bb = vT + b * 1024L * 4096 + bn * 4096 + sp * 2048;
  NE_SETUP_PTRS(Ab, Bb, 4096);
  u16* part = (b ? pB : pA) + (long)sp * 4096 * 1024;

  NE_START()
  for (int T = 0; T < 64; ++T) NE_TILE(T, 64)

#pragma unroll
  for (int mi = 0; mi < 8; ++mi) {
    long row = bm + wm + mi * 16 + fr;
#pragma unroll
    for (int ni = 0; ni < 4; ++ni) {
      long colb = bn + wn + ni * 16 + oc;
      ushort4 o;
      o.x = f2bf(acc[mi][ni][0]);
      o.y = f2bf(acc[mi][ni][1]);
      o.z = f2bf(acc[mi][ni][2]);
      o.w = f2bf(acc[mi][ni][3]);
      *(ushort4*)(part + row * 1024 + colb) = o;
    }
  }
}

// Fused QKV projection — phased 256^2 engine. A=xb [8192,1024],
// Bt=WqkvT [3072,1024]. Grid (8,48) = 384 blocks x 512 thr (1.5 rounds).
// xcd = blockIdx.x owns A-rows [xcd*1024, +1024) (2MB, L2-resident) and
// sweeps 12 n-tiles m-fastest. Block-uniform: bx<8 -> q/k (swapped epi,
// ushort4 along d); bx>=8 -> v (non-swapped epi, ushort4 along s into vT).
__global__ __launch_bounds__(512, 2) void gemm_qkv(
    const u16* __restrict__ A, const u16* __restrict__ Bt,
    u16* __restrict__ qb, u16* __restrict__ kb, u16* __restrict__ vT,
    const float* __restrict__ bq, const float* __restrict__ bk,
    const float* __restrict__ bv)
{
  const int xcd = blockIdx.x;
  const int j = blockIdx.y;                 // [0,48)
  const int by = xcd * 4 + (j & 3);         // [0,32)
  const int bx = j >> 2;                    // [0,12)

  NE_PROLOGUE((long)by * 256, (long)bx * 256);
  const u16* Ab = A + bm * 1024;
  const u16* Bb = Bt + bn * 1024;
  NE_SETUP_PTRS(Ab, Bb, 1024);

  if (bn < 2048) {
    NE_START()
    for (int T = 0; T < 32; ++T) NE_TILE(T, 32)
    u16* C = (bn < 1024) ? qb : kb;
    const float* bias = (bn < 1024) ? bq : bk;
#pragma unroll
    for (int mi = 0; mi < 8; ++mi) {
      long row = bm + wm + mi * 16 + fr;
#pragma unroll
      for (int ni = 0; ni < 4; ++ni) {
        long colg = bn + wn + ni * 16 + oc;
        long cc = colg & 1023;
        float4 bv4 = *(const float4*)(bias + cc);
        ushort4 o;
        o.x = f2bf(acc[mi][ni][0] + bv4.x);
        o.y = f2bf(acc[mi][ni][1] + bv4.y);
        o.z = f2bf(acc[mi][ni][2] + bv4.z);
        o.w = f2bf(acc[mi][ni][3] + bv4.w);
        *(ushort4*)(C + row * 1024 + cc) = o;
      }
    }
  } else {
    NE_START()
    for (int T = 0; T < 32; ++T) NE_TILE_NS(T, 32)
    const int orow = (lane >> 4) * 4;       // non-swapped: 4 consecutive rows
    const long b_ = bm >> 12;               // block entirely in one batch
    const long s0 = (bm & 4095) + wm;
    u16* vb = vT + b_ * (1024L * 4096);
#pragma unroll
    for (int ni = 0; ni < 4; ++ni) {
      long d = bn + wn + ni * 16 + fr - 2048;
      float bvv = bv[d];
#pragma unroll
      for (int mi = 0; mi < 8; ++mi) {
        long s = s0 + mi * 16 + orow;
        ushort4 o;
        o.x = f2bf(acc[mi][ni][0] + bvv);
        o.y = f2bf(acc[mi][ni][1] + bvv);
        o.z = f2bf(acc[mi][ni][2] + bvv);
        o.w = f2bf(acc[mi][ni][3] + bvv);
        *(ushort4*)(vb + d * 4096L + s) = o;
      }
    }
  }
}

// Combined reduce + softmax-normalize: grid (4096 rows, 2 batches).
__global__ __launch_bounds__(256) void reduce2_div_row(
    const u16* __restrict__ pA, const u16* __restrict__ pB,
    const float* __restrict__ lpartT, u16* __restrict__ ob)
{
  const int row = blockIdx.x;           // [0,4096)
  const long b = blockIdx.y;
  const int tid = threadIdx.x;
  const u16* part = b ? pB : pA;
  const float* lp = lpartT + b * 4096 * 64;
  __shared__ float sl;
  if (tid < 64) {
    float s = lp[(long)row * 64 + tid];
#pragma unroll
    for (int off = 32; off; off >>= 1) s += __shfl_down(s, off);
    if (tid == 0) sl = s;
  }
  __syncthreads();
  const float inv = 1.0f / sl;
  const long base = (long)row * 1024 + tid * 4;
  float acc4[4] = {0.f, 0.f, 0.f, 0.f};
#pragma unroll
  for (int s = 0; s < 2; ++s) {
    ushort4 p = *(const ushort4*)(part + (long)s * 4096 * 1024 + base);
    acc4[0] += bf2f(p.x); acc4[1] += bf2f(p.y);
    acc4[2] += bf2f(p.z); acc4[3] += bf2f(p.w);
  }
  ushort4 o;
  o.x = f2bf(acc4[0] * inv);
  o.y = f2bf(acc4[1] * inv);
  o.z = f2bf(acc4[2] * inv);
  o.w = f2bf(acc4[3] * inv);
  *(ushort4*)(ob + b * 4096L * 1024 + base) = o;
}

// Fused prep: blocks [0,8192) cast x (fp32->bf16, float4); blocks
// [8192,12288) transpose+cast the 4 weight matrices (z = (blk-8192)>>10).
__global__ __launch_bounds__(256) void prep(
    const float* __restrict__ x, u16* __restrict__ xb,
    const float* __restrict__ W0, const float* __restrict__ W1,
    const float* __restrict__ W2, const float* __restrict__ W3,
    u16* __restrict__ O0, u16* __restrict__ O1,
    u16* __restrict__ O2, u16* __restrict__ O3)
{
  __shared__ float tile[32][33];
  int blk = blockIdx.x;
  if (blk < 8192) {
    int i = blk * 256 + threadIdx.x;      // 2M float4s
    float4 f = ((const float4*)x)[i];
    ushort4 o;
    o.x = f2bf(f.x); o.y = f2bf(f.y); o.z = f2bf(f.z); o.w = f2bf(f.w);
    ((ushort4*)xb)[i] = o;
  } else {
    blk -= 8192;
    const int z = blk >> 10, t = blk & 1023;
    const float* in = (z == 0) ? W0 : (z == 1) ? W1 : (z == 2) ? W2 : W3;
    u16* outp = (z == 0) ? O0 : (z == 1) ? O1 : (z == 2) ? O2 : O3;
    const int bx = (t & 31) * 32, by = (t >> 5) * 32;
    const int tx = threadIdx.x & 31, ty = threadIdx.x >> 5;   // 32 x 8
    for (int i = ty; i < 32; i += 8)
      tile[i][tx] = in[(long)(by + i) * 1024 + bx + tx];
    __syncthreads();
    for (int i = ty; i < 32; i += 8)
      outp[(long)(bx + i) * 1024 + by + tx] = f2bf(tile[tx][i]);
  }
}

extern "C" void kernel_launch(void* const* d_in, const int* in_sizes, int n_in,
                              void* d_out, int out_size, void* d_ws, size_t ws_size,
                              hipStream_t stream) {
  const float* x  = (const float*)d_in[0];
  const float* Wq = (const float*)d_in[1];
  const float* bq = (const float*)d_in[2];
  const float* Wk = (const float*)d_in[3];
  const float* bk = (const float*)d_in[4];
  const float* Wv = (const float*)d_in[5];
  const float* bv = (const float*)d_in[6];
  const float* Wo = (const float*)d_in[7];
  const float* bo = (const float*)d_in[8];
  float* out = (float*)d_out;

  const int B = 2, S = 4096, D = 1024;
  const long MS = (long)B * S;  // 8192
  const long MB = 1L << 20;

  // ---- workspace layout (top usage 152 MiB; ws_size >= 168 MiB proven) ----
  //  [0,16M)    qb  bf16 [8192,1024]   -- dead after QK_exp; reused as
  //                                       PV bf16 partials batch0 [2][4096][1024]
  //  [16,32M)   kb  bf16 [8192,1024]
  //  [32,48M)   vT  bf16 [B][1024][4096]
  //  [48,64M)   xb  bf16 [8192,1024]   -- aliased with ob (xb dead before PV)
  //  [64,72M)   WqkvT bf16 [3072,1024] + WoT bf16 [1024,1024]
  //  [72,136M)  probs bf16 [B][4096][4096]  (both batches)
  //  [136,152M) PV bf16 partials batch1 [2][4096][1024]
  // d_out (32MB fp32, dead until final proj) hosts lpartT [B][4096][64] fp32.
  char* w = (char*)d_ws;
  u16* qb  = (u16*)(w);
  u16* kb  = (u16*)(w + 16 * MB);
  u16* vT  = (u16*)(w + 32 * MB);
  u16* xb  = (u16*)(w + 48 * MB);
  u16* ob  = xb;                        // alias: xb dead before ob written
  u16* WqkvT = (u16*)(w + 64 * MB);
  u16* WoT = WqkvT + 3072L * 1024;
  u16* probs = (u16*)(w + 72 * MB);
  u16* partA = (u16*)(w);               // over qb, dead after QK_exp
  u16* partB = (u16*)(w + 136 * MB);
  float* lpartT = (float*)d_out;        // [2][4096][64] fp32 = 2MB

  // 1. fused prep: cast x + transpose/cast all 4 weights
  prep<<<dim3(8192 + 4096), 256, 0, stream>>>(
      x, xb, Wq, Wk, Wv, Wo,
      WqkvT, WqkvT + 1024L * 1024, WqkvT + 2048L * 1024, WoT);

  // 2. fused QKV projection: grid (8,48) = 384 blocks (new engine)
  gemm_qkv<<<dim3(8, 48), 512, 0, stream>>>(
      xb, WqkvT, qb, kb, vT, bq, bk, bv);

  // 3. attention, both batches per launch (new phased engine)
  const float scale = 0.125f;  // 1/sqrt(64)
  gemm_qk_exp<<<dim3(8, 64), 512, 0, stream>>>(
      qb, kb, probs, lpartT, scale);
  // qb now dead -> partA overlays it
  gemm_pv_splitk2<<<dim3(8, 32), 512, 0, stream>>>(
      probs, vT, partA, partB);
  reduce2_div_row<<<dim3(S, B), 256, 0, stream>>>(partA, partB, lpartT, ob);

  // 4. final projection -> fp32 d_out (overwrites lpartT scratch)
  gemm_bt<<<dim3(D / 128, MS / 128), 256, 0, stream>>>(ob, WoT, out, bo, D, D);
}